// Round 4
// baseline (635.197 us; speedup 1.0000x reference)
//
#include <hip/hip_runtime.h>

// Problem constants
constexpr int kE = 65536, kNTOT = 8192;

// ---------------- threefry2x32 (JAX-exact, 20 rounds) ----------------
__host__ __device__ __forceinline__ void tf_round(unsigned& x0, unsigned& x1, int r) {
  x0 += x1;
  x1 = (x1 << r) | (x1 >> (32 - r));
  x1 ^= x0;
}
__host__ __device__ __forceinline__ void tf2x32(unsigned k0, unsigned k1,
                                                unsigned& x0, unsigned& x1) {
  unsigned ks2 = k0 ^ k1 ^ 0x1BD11BDAu;
  x0 += k0; x1 += k1;
  tf_round(x0,x1,13); tf_round(x0,x1,15); tf_round(x0,x1,26); tf_round(x0,x1,6);
  x0 += k1; x1 += ks2 + 1u;
  tf_round(x0,x1,17); tf_round(x0,x1,29); tf_round(x0,x1,16); tf_round(x0,x1,24);
  x0 += ks2; x1 += k0 + 2u;
  tf_round(x0,x1,13); tf_round(x0,x1,15); tf_round(x0,x1,26); tf_round(x0,x1,6);
  x0 += k0; x1 += k1 + 3u;
  tf_round(x0,x1,17); tf_round(x0,x1,29); tf_round(x0,x1,16); tf_round(x0,x1,24);
  x0 += k1; x1 += ks2 + 4u;
  tf_round(x0,x1,13); tf_round(x0,x1,15); tf_round(x0,x1,26); tf_round(x0,x1,6);
  x0 += ks2; x1 += k0 + 5u;
}

// bits -> N(0,1), replicating jax.random.normal f32 path (partitionable threefry)
__device__ __forceinline__ float bits_to_normal(unsigned bits) {
  float f = __uint_as_float((bits >> 9) | 0x3f800000u) - 1.0f;  // [0,1)
  const float LO = -0.99999994f;
  float u = fmaf(f, 2.0f, LO);
  u = fmaxf(u, LO);
  float w = -log1pf(-u * u);
  float p;
  if (w < 5.0f) {
    w -= 2.5f;
    p = 2.81022636e-08f;
    p = fmaf(p, w, 3.43273939e-07f);
    p = fmaf(p, w, -3.5233877e-06f);
    p = fmaf(p, w, -4.39150654e-06f);
    p = fmaf(p, w, 0.00021858087f);
    p = fmaf(p, w, -0.00125372503f);
    p = fmaf(p, w, -0.00417768164f);
    p = fmaf(p, w, 0.246640727f);
    p = fmaf(p, w, 1.50140941f);
  } else {
    w = sqrtf(w) - 3.0f;
    p = -0.000200214257f;
    p = fmaf(p, w, 0.000100950558f);
    p = fmaf(p, w, 0.00134934322f);
    p = fmaf(p, w, -0.00367342844f);
    p = fmaf(p, w, 0.00573950773f);
    p = fmaf(p, w, -0.0076224613f);
    p = fmaf(p, w, 0.00943887047f);
    p = fmaf(p, w, 1.00167406f);
    p = fmaf(p, w, 2.83297682f);
  }
  return 1.41421356f * (p * u);
}

// ================= CSR build (once per launch; edge_index reused 4x) =================
__global__ __launch_bounds__(256) void hist_kern(const int* __restrict__ eiR,
                                                 const int* __restrict__ eiP,
                                                 int* __restrict__ cntR,
                                                 int* __restrict__ cntP) {
  int i = blockIdx.x * 256 + threadIdx.x;  // 0..131071
  const int* ei = (i < kE) ? eiR : eiP;
  int* cnt = (i < kE) ? cntR : cntP;
  int e = i & (kE - 1);
  atomicAdd(&cnt[ei[kE + e]], 1);
}

// 2 blocks (one per graph), 256 threads: 32 elems/thread + hierarchical block scan
__global__ __launch_bounds__(256) void scan_kern(const int* __restrict__ cntR,
                                                 int* __restrict__ rpR, int* __restrict__ offR,
                                                 const int* __restrict__ cntP,
                                                 int* __restrict__ rpP, int* __restrict__ offP) {
  const int* cnt = blockIdx.x ? cntP : cntR;
  int* rp = blockIdx.x ? rpP : rpR;
  int* off = blockIdx.x ? offP : offR;
  int t = threadIdx.x;
  int base = t * 32;
  int v[32];
#pragma unroll
  for (int i = 0; i < 32; ++i) v[i] = cnt[base + i];
  int sum = 0;
#pragma unroll
  for (int i = 0; i < 32; ++i) sum += v[i];
  int lane = t & 63, w = t >> 6;
  int incl = sum;
#pragma unroll
  for (int o = 1; o < 64; o <<= 1) {
    int y = __shfl_up(incl, o);
    if (lane >= o) incl += y;
  }
  __shared__ int wsum[4];
  if (lane == 63) wsum[w] = incl;
  __syncthreads();
  int woff = 0;
#pragma unroll
  for (int i = 0; i < 4; ++i) if (i < w) woff += wsum[i];
  int running = woff + incl - sum;
#pragma unroll
  for (int i = 0; i < 32; ++i) {
    rp[base + i] = running;
    off[base + i] = running;
    running += v[i];
  }
  if (t == 0) rp[kNTOT] = kE;
}

__global__ __launch_bounds__(256) void scatter_kern(
    const int* __restrict__ eiR, const int* __restrict__ eiP,
    int* __restrict__ offR, int* __restrict__ offP,
    int* __restrict__ permR, int* __restrict__ permP,
    int* __restrict__ srcsR, int* __restrict__ srcsP) {
  int i = blockIdx.x * 256 + threadIdx.x;
  const int* ei = (i < kE) ? eiR : eiP;
  int* off = (i < kE) ? offR : offP;
  int* perm = (i < kE) ? permR : permP;
  int* srcs = (i < kE) ? srcsR : srcsP;
  int e = i & (kE - 1);
  int dst = ei[kE + e];
  int pos = atomicAdd(&off[dst], 1);
  perm[pos] = e;
  srcs[pos] = ei[e];
}

// ================= msg GEMM (both graphs): msg[i] = relu(x[srcs[i]]@Wm + ef[perm[i]]@We)
// blocks [0,1024) = graph r, [1024,2048) = graph p. 64 edges x 64 outs, K = KX+16.
template <int KX>
__global__ __launch_bounds__(256) void msg_gemm(
    const float* __restrict__ xR, const float* __restrict__ efR,
    const int* __restrict__ srcsR, const int* __restrict__ permR,
    float* __restrict__ msgR,
    const float* __restrict__ xP, const float* __restrict__ efP,
    const int* __restrict__ srcsP, const int* __restrict__ permP,
    float* __restrict__ msgP,
    const float* __restrict__ Wm, const float* __restrict__ We) {
  constexpr int KT = KX + 16;
  __shared__ float sA[KT][68];   // transposed A-tile: [k][edge]
  __shared__ float sW[KT][68];   // [k][j]
  bool isP = blockIdx.x >= 1024;
  const float* x = isP ? xP : xR;
  const float* ef = isP ? efP : efR;
  const int* srcs = isP ? srcsP : srcsR;
  const int* perm = isP ? permP : permR;
  float* msg = isP ? msgP : msgR;
  int i0 = (blockIdx.x & 1023) * 64;
  int t = threadIdx.x;
#pragma unroll
  for (int idx = 0; idx < KT * 64 / 1024; ++idx) {
    int q = t * 4 + idx * 1024;
    int k = q >> 6, j = q & 63;
    const float* sp = (k < KX) ? (Wm + k * 64 + j) : (We + (k - KX) * 64 + j);
    float4 v = *reinterpret_cast<const float4*>(sp);
    *reinterpret_cast<float4*>(&sW[k][j]) = v;
  }
#pragma unroll
  for (int idx = 0; idx < KT * 64 / 1024; ++idx) {
    int q = t * 4 + idx * 1024;
    int r = q / KT;
    int k = q % KT;   // 4-aligned
    const float* rptr = (k < KX) ? (x + (size_t)srcs[i0 + r] * KX + k)
                                 : (ef + (size_t)perm[i0 + r] * 16 + (k - KX));
    float4 v = *reinterpret_cast<const float4*>(rptr);
    sA[k + 0][r] = v.x; sA[k + 1][r] = v.y; sA[k + 2][r] = v.z; sA[k + 3][r] = v.w;
  }
  __syncthreads();
  int tn = (t & 15) * 4;
  int tj = (t >> 4) * 4;
  float acc[4][4] = {};
#pragma unroll 8
  for (int k = 0; k < KT; ++k) {
    float4 a = *reinterpret_cast<const float4*>(&sA[k][tn]);
    float4 b = *reinterpret_cast<const float4*>(&sW[k][tj]);
    acc[0][0] = fmaf(a.x, b.x, acc[0][0]); acc[0][1] = fmaf(a.x, b.y, acc[0][1]);
    acc[0][2] = fmaf(a.x, b.z, acc[0][2]); acc[0][3] = fmaf(a.x, b.w, acc[0][3]);
    acc[1][0] = fmaf(a.y, b.x, acc[1][0]); acc[1][1] = fmaf(a.y, b.y, acc[1][1]);
    acc[1][2] = fmaf(a.y, b.z, acc[1][2]); acc[1][3] = fmaf(a.y, b.w, acc[1][3]);
    acc[2][0] = fmaf(a.z, b.x, acc[2][0]); acc[2][1] = fmaf(a.z, b.y, acc[2][1]);
    acc[2][2] = fmaf(a.z, b.z, acc[2][2]); acc[2][3] = fmaf(a.z, b.w, acc[2][3]);
    acc[3][0] = fmaf(a.w, b.x, acc[3][0]); acc[3][1] = fmaf(a.w, b.y, acc[3][1]);
    acc[3][2] = fmaf(a.w, b.z, acc[3][2]); acc[3][3] = fmaf(a.w, b.w, acc[3][3]);
  }
#pragma unroll
  for (int i = 0; i < 4; ++i) {
    float4 o;
    o.x = fmaxf(acc[i][0], 0.f); o.y = fmaxf(acc[i][1], 0.f);
    o.z = fmaxf(acc[i][2], 0.f); o.w = fmaxf(acc[i][3], 0.f);
    *reinterpret_cast<float4*>(&msg[(size_t)(i0 + tn + i) * 64 + tj]) = o;
  }
}

// ---------------- gnn1 node (fused segment-sum): h = relu(x@Ws + sum msg + b) --------
__global__ __launch_bounds__(256) void node1_kern(
    const float* __restrict__ xR, const float* __restrict__ msgR,
    const int* __restrict__ rpR, float* __restrict__ hR,
    const float* __restrict__ xP, const float* __restrict__ msgP,
    const int* __restrict__ rpP, float* __restrict__ hP,
    const float* __restrict__ Ws, const float* __restrict__ bias) {
  int lane = threadIdx.x & 63;
  int wv = blockIdx.x * 4 + (threadIdx.x >> 6);  // 0..1023
  float wcol[64];
#pragma unroll
  for (int k = 0; k < 64; ++k) wcol[k] = Ws[k * 64 + lane];
  float bv = bias[lane];
  const float* x; const float* msg; const int* rp; float* h; int base;
  if (wv < 512) { x = xR; msg = msgR; rp = rpR; h = hR; base = wv * 16; }
  else { x = xP; msg = msgP; rp = rpP; h = hP; base = (wv - 512) * 16; }
  for (int n = base; n < base + 16; ++n) {
    int s = rp[n], e = rp[n + 1];
    float acc = bv;
    for (int i = s; i < e; ++i) acc += msg[(size_t)i * 64 + lane];
    const float4* xr = reinterpret_cast<const float4*>(x + (size_t)n * 64);
#pragma unroll
    for (int k4 = 0; k4 < 16; ++k4) {
      float4 v = xr[k4];
      acc = fmaf(v.x, wcol[4 * k4 + 0], acc);
      acc = fmaf(v.y, wcol[4 * k4 + 1], acc);
      acc = fmaf(v.z, wcol[4 * k4 + 2], acc);
      acc = fmaf(v.w, wcol[4 * k4 + 3], acc);
    }
    h[(size_t)n * 64 + lane] = fmaxf(acc, 0.f);
  }
}

// ---------------- M_hat[b,r,p] = sum_d h_r[b,r,d]*h_p[b,p,d] ----------------
__global__ __launch_bounds__(64) void mhat_kern(const float* __restrict__ hR,
                                                const float* __restrict__ hP,
                                                float* __restrict__ Mhat) {
  __shared__ float hr[16][66];
  __shared__ float hp[128][66];
  int b = blockIdx.x >> 3;
  int r0 = (blockIdx.x & 7) * 16;
  int t = threadIdx.x;
  const float* hrG = hR + ((size_t)b * 128 + r0) * 64;
#pragma unroll
  for (int s = 0; s < 16; ++s) { int i = t + 64 * s; hr[i >> 6][i & 63] = hrG[i]; }
  const float* hpG = hP + (size_t)b * 128 * 64;
#pragma unroll 8
  for (int s = 0; s < 128; ++s) { int i = t + 64 * s; hp[i >> 6][i & 63] = hpG[i]; }
  __syncthreads();
  int tx = t & 31;
  int ty = t >> 5;
  float acc[8][4] = {};
  for (int d = 0; d < 64; ++d) {
    float a[8], bb[4];
#pragma unroll
    for (int ii = 0; ii < 8; ++ii) a[ii] = hr[ty + 2 * ii][d];
#pragma unroll
    for (int i = 0; i < 4; ++i) bb[i] = hp[tx + 32 * i][d];
#pragma unroll
    for (int ii = 0; ii < 8; ++ii)
#pragma unroll
      for (int i = 0; i < 4; ++i) acc[ii][i] = fmaf(a[ii], bb[i], acc[ii][i]);
  }
  float* outp = Mhat + ((size_t)b * 128 + r0) * 128;
#pragma unroll
  for (int ii = 0; ii < 8; ++ii)
#pragma unroll
    for (int i = 0; i < 4; ++i)
      outp[(size_t)(ty + 2 * ii) * 128 + tx + 32 * i] = acc[ii][i];
}

// ======== fused per-batch: RNG (threefry) + softmax(Mhat[b]) + rf_p = M^T @ rf_r ========
// 64 blocks (one per batch), 256 threads. Mhat tile + rf_r tile live in LDS.
__global__ __launch_bounds__(256) void softrfp_kern(
    const float* __restrict__ Mhat, float* __restrict__ M0out,
    float* __restrict__ rfr, float* __restrict__ rfp,
    unsigned fk0, unsigned fk1) {
  __shared__ __align__(16) float sM[128][132];
  __shared__ __align__(16) float rr[128][32];
  int b = blockIdx.x;
  int t = threadIdx.x;
  // RNG: this batch's 4096 normals -> LDS + global (for msg_gemm/node2u gathers)
  unsigned gbase = (unsigned)b * 4096u;
#pragma unroll
  for (int q = 0; q < 16; ++q) {
    int il = q * 256 + t;
    unsigned x0 = 0u, x1 = gbase + (unsigned)il;   // counter (hi,lo) = (0, i)
    tf2x32(fk0, fk1, x0, x1);
    float nv = bits_to_normal(x0 ^ x1);
    rr[il >> 5][il & 31] = nv;
    rfr[gbase + il] = nv;
  }
  // load Mhat[b] (128x128) into LDS
  const float4* src = reinterpret_cast<const float4*>(Mhat + (size_t)b * 16384);
#pragma unroll
  for (int q = 0; q < 16; ++q) {
    int idx = q * 256 + t;                 // float4 index, 4096 total
    float4 v = src[idx];
    *reinterpret_cast<float4*>(&sM[idx >> 5][(idx & 31) * 4]) = v;
  }
  __syncthreads();
  // softmax rows (each wave owns rows w, w+4, ...)
  int lane = t & 63, w = t >> 6;
  for (int row = w; row < 128; row += 4) {
    float v0 = sM[row][2 * lane], v1 = sM[row][2 * lane + 1];
    float mx = fmaxf(v0, v1);
#pragma unroll
    for (int o = 32; o > 0; o >>= 1) mx = fmaxf(mx, __shfl_xor(mx, o));
    float e0 = __expf(v0 - mx), e1 = __expf(v1 - mx);
    float s = e0 + e1;
#pragma unroll
    for (int o = 32; o > 0; o >>= 1) s += __shfl_xor(s, o);
    float inv = 1.0f / s;
    sM[row][2 * lane] = e0 * inv;
    sM[row][2 * lane + 1] = e1 * inv;
  }
  __syncthreads();
  // iteration 0: M_0 output straight from LDS
  if (M0out) {
    float4* dst = reinterpret_cast<float4*>(M0out + (size_t)b * 16384);
#pragma unroll
    for (int q = 0; q < 16; ++q) {
      int idx = q * 256 + t;
      dst[idx] = *reinterpret_cast<const float4*>(&sM[idx >> 5][(idx & 31) * 4]);
    }
  }
  // rf_p[b,p,:] = sum_r M[r][p] * rr[r][:]
  int p = t >> 1, hf = t & 1;
  float acc[16] = {};
  for (int r = 0; r < 128; ++r) {
    float m = sM[r][p];
#pragma unroll
    for (int i = 0; i < 16; ++i) acc[i] = fmaf(m, rr[r][hf * 16 + i], acc[i]);
  }
  float4* dst = reinterpret_cast<float4*>(rfp + ((size_t)b * 128 + p) * 32 + hf * 16);
  dst[0] = make_float4(acc[0], acc[1], acc[2], acc[3]);
  dst[1] = make_float4(acc[4], acc[5], acc[6], acc[7]);
  dst[2] = make_float4(acc[8], acc[9], acc[10], acc[11]);
  dst[3] = make_float4(acc[12], acc[13], acc[14], acc[15]);
}

// ---------------- final softmax (rows of 128) -> out ----------------
__global__ __launch_bounds__(256) void softmax_out_kern(
    const float* __restrict__ Mhat, float* __restrict__ outDst) {
  int lane = threadIdx.x & 63;
  int row = blockIdx.x * 4 + (threadIdx.x >> 6);
  const float2* src = reinterpret_cast<const float2*>(Mhat + (size_t)row * 128);
  float2 v = src[lane];
  float mx = fmaxf(v.x, v.y);
#pragma unroll
  for (int o = 32; o > 0; o >>= 1) mx = fmaxf(mx, __shfl_xor(mx, o));
  float e0 = __expf(v.x - mx), e1 = __expf(v.y - mx);
  float s = e0 + e1;
#pragma unroll
  for (int o = 32; o > 0; o >>= 1) s += __shfl_xor(s, o);
  float inv = 1.0f / s;
  float2 r2; r2.x = e0 * inv; r2.y = e1 * inv;
  reinterpret_cast<float2*>(outDst + (size_t)row * 128)[lane] = r2;
}

// ---------------- gnn2 node (fused segment-sum) + @W1 fusion ----------------
__global__ __launch_bounds__(256) void node2u_kern(
    const float* __restrict__ rfR, const float* __restrict__ msgR,
    const int* __restrict__ rpR, float* __restrict__ uR,
    const float* __restrict__ rfP, const float* __restrict__ msgP,
    const int* __restrict__ rpP, float* __restrict__ uP,
    const float* __restrict__ Ws2, const float* __restrict__ b2g,
    const float* __restrict__ W1, const float* __restrict__ b1) {
  __shared__ float ost[4][64];
  int lane = threadIdx.x & 63;
  int wl = threadIdx.x >> 6;
  int wv = blockIdx.x * 4 + wl;
  float ws2[32];
#pragma unroll
  for (int k = 0; k < 32; ++k) ws2[k] = Ws2[k * 64 + lane];
  float w1c[64];
#pragma unroll
  for (int k = 0; k < 64; ++k) w1c[k] = W1[k * 64 + lane];
  float bgv = b2g[lane];
  const float* rf; const float* msg; const int* rp; float* u; float uinit; int base;
  if (wv < 512) { rf = rfR; msg = msgR; rp = rpR; u = uR; base = wv * 16; uinit = b1[lane]; }
  else { rf = rfP; msg = msgP; rp = rpP; u = uP; base = (wv - 512) * 16; uinit = 0.f; }
  for (int n = base; n < base + 16; ++n) {
    int s = rp[n], e = rp[n + 1];
    float acc = bgv;
    for (int i = s; i < e; ++i) acc += msg[(size_t)i * 64 + lane];
    const float4* xr = reinterpret_cast<const float4*>(rf + (size_t)n * 32);
#pragma unroll
    for (int k4 = 0; k4 < 8; ++k4) {
      float4 v = xr[k4];
      acc = fmaf(v.x, ws2[4 * k4 + 0], acc);
      acc = fmaf(v.y, ws2[4 * k4 + 1], acc);
      acc = fmaf(v.z, ws2[4 * k4 + 2], acc);
      acc = fmaf(v.w, ws2[4 * k4 + 3], acc);
    }
    float o = fmaxf(acc, 0.f);
    ost[wl][lane] = o;
    float uacc = uinit;
    const float4* orow = reinterpret_cast<const float4*>(&ost[wl][0]);
#pragma unroll
    for (int k4 = 0; k4 < 16; ++k4) {
      float4 v = orow[k4];
      uacc = fmaf(v.x, w1c[4 * k4 + 0], uacc);
      uacc = fmaf(v.y, w1c[4 * k4 + 1], uacc);
      uacc = fmaf(v.z, w1c[4 * k4 + 2], uacc);
      uacc = fmaf(v.w, w1c[4 * k4 + 3], uacc);
    }
    u[(size_t)n * 64 + lane] = uacc;
  }
}

// ---------------- upd: M_hat[b,r,p] += sum_j relu(u_r[r,j]-u_p[p,j])*W2[j] + b2 ------
__global__ __launch_bounds__(128) void upd_kern(
    const float* __restrict__ uR, const float* __restrict__ uP,
    const float* __restrict__ W2, const float* __restrict__ b2p,
    float* __restrict__ Mhat) {
  __shared__ float sur[16][66];
  __shared__ float sup[128][66];
  __shared__ float sw2[64];
  int b = blockIdx.x >> 3;
  int r0 = (blockIdx.x & 7) * 16;
  int t = threadIdx.x;
  const float* urG = uR + ((size_t)b * 128 + r0) * 64;
#pragma unroll
  for (int s = 0; s < 8; ++s) { int i = t + 128 * s; sur[i >> 6][i & 63] = urG[i]; }
  const float* upG = uP + (size_t)b * 128 * 64;
#pragma unroll 8
  for (int s = 0; s < 64; ++s) { int i = t + 128 * s; sup[i >> 6][i & 63] = upG[i]; }
  if (t < 64) sw2[t] = W2[t];
  __syncthreads();
  int tx = t & 31, ty = t >> 5;
  float acc[4][4] = {};
  for (int j = 0; j < 64; ++j) {
    float w2v = sw2[j];
    float a[4], bb[4];
#pragma unroll
    for (int ii = 0; ii < 4; ++ii) a[ii] = sur[ty + 4 * ii][j];
#pragma unroll
    for (int i = 0; i < 4; ++i) bb[i] = sup[tx + 32 * i][j];
#pragma unroll
    for (int ii = 0; ii < 4; ++ii)
#pragma unroll
      for (int i = 0; i < 4; ++i)
        acc[ii][i] = fmaf(fmaxf(a[ii] - bb[i], 0.f), w2v, acc[ii][i]);
  }
  float b2v = b2p[0];
  float* mrow = Mhat + ((size_t)b * 128 + r0) * 128;
#pragma unroll
  for (int ii = 0; ii < 4; ++ii) {
    int r = ty + 4 * ii;
#pragma unroll
    for (int i = 0; i < 4; ++i) {
      int p = tx + 32 * i;
      mrow[(size_t)r * 128 + p] += acc[ii][i] + b2v;
    }
  }
}

extern "C" void kernel_launch(void* const* d_in, const int* in_sizes, int n_in,
                              void* d_out, int out_size, void* d_ws, size_t ws_size,
                              hipStream_t stream) {
  (void)in_sizes; (void)n_in; (void)out_size; (void)ws_size;
  const float* x_r  = (const float*)d_in[0];
  const int*   ei_r = (const int*)d_in[1];
  const float* ef_r = (const float*)d_in[2];
  const float* x_p  = (const float*)d_in[3];
  const int*   ei_p = (const int*)d_in[4];
  const float* ef_p = (const float*)d_in[5];
  const float* g1_Ws = (const float*)d_in[8];
  const float* g1_Wm = (const float*)d_in[9];
  const float* g1_We = (const float*)d_in[10];
  const float* g1_b  = (const float*)d_in[11];
  const float* g2_Ws = (const float*)d_in[12];
  const float* g2_Wm = (const float*)d_in[13];
  const float* g2_We = (const float*)d_in[14];
  const float* g2_b  = (const float*)d_in[15];
  const float* W1 = (const float*)d_in[16];
  const float* b1 = (const float*)d_in[17];
  const float* W2 = (const float*)d_in[18];
  const float* b2 = (const float*)d_in[19];
  float* out = (float*)d_out;

  float* ws = (float*)d_ws;
  float* h_r   = ws;                 // 524288
  float* h_p   = h_r + 524288;       // 524288
  float* Mhat  = h_p + 524288;       // 1048576
  float* rfr   = Mhat + 1048576;     // 262144
  float* rfp   = rfr + 262144;       // 262144
  float* u_r   = rfp + 262144;       // 524288
  float* u_p   = u_r + 524288;       // 524288
  float* msg_r = u_p + 524288;       // 4194304
  float* msg_p = msg_r + 4194304;    // 4194304
  int* ib      = (int*)(msg_p + 4194304);
  int* cnt_r  = ib;                  // 8192
  int* cnt_p  = cnt_r + 8192;        // 8192
  int* off_r  = cnt_p + 8192;        // 8192
  int* off_p  = off_r + 8192;        // 8192
  int* rp_r   = off_p + 8192;        // 8193
  int* rp_p   = rp_r + 8193;         // 8193
  int* perm_r = rp_p + 8193;         // 65536
  int* perm_p = perm_r + 65536;      // 65536
  int* srcs_r = perm_p + 65536;      // 65536
  int* srcs_p = srcs_r + 65536;      // 65536

  // ---- CSR build (once; reused by all 4 message passes) ----
  hipMemsetAsync(cnt_r, 0, 2 * 8192 * sizeof(int), stream);
  hist_kern<<<512, 256, 0, stream>>>(ei_r, ei_p, cnt_r, cnt_p);
  scan_kern<<<2, 256, 0, stream>>>(cnt_r, rp_r, off_r, cnt_p, rp_p, off_p);
  scatter_kern<<<512, 256, 0, stream>>>(ei_r, ei_p, off_r, off_p,
                                        perm_r, perm_p, srcs_r, srcs_p);

  // ---- gnn1 (both graphs in each dispatch) ----
  msg_gemm<64><<<2048, 256, 0, stream>>>(x_r, ef_r, srcs_r, perm_r, msg_r,
                                         x_p, ef_p, srcs_p, perm_p, msg_p,
                                         g1_Wm, g1_We);
  node1_kern<<<256, 256, 0, stream>>>(x_r, msg_r, rp_r, h_r,
                                      x_p, msg_p, rp_p, h_p, g1_Ws, g1_b);
  mhat_kern<<<512, 64, 0, stream>>>(h_r, h_p, Mhat);

  for (int it = 0; it < 3; ++it) {
    unsigned fk0 = 0u, fk1 = (unsigned)it;
    tf2x32(0u, 42u, fk0, fk1);   // folded key, host-side
    softrfp_kern<<<64, 256, 0, stream>>>(Mhat, it == 0 ? out : nullptr,
                                         rfr, rfp, fk0, fk1);
    msg_gemm<32><<<2048, 256, 0, stream>>>(rfr, ef_r, srcs_r, perm_r, msg_r,
                                           rfp, ef_p, srcs_p, perm_p, msg_p,
                                           g2_Wm, g2_We);
    node2u_kern<<<256, 256, 0, stream>>>(rfr, msg_r, rp_r, u_r,
                                         rfp, msg_p, rp_p, u_p,
                                         g2_Ws, g2_b, W1, b1);
    upd_kern<<<512, 128, 0, stream>>>(u_r, u_p, W2, b2, Mhat);
  }
  softmax_out_kern<<<2048, 256, 0, stream>>>(Mhat, out + 1048576);
}

// Round 5
// 443.843 us; speedup vs baseline: 1.4311x; 1.4311x over previous
//
#include <hip/hip_runtime.h>

// Problem constants
constexpr int kE = 65536, kNTOT = 8192;

// ---------------- threefry2x32 (JAX-exact, 20 rounds) ----------------
__host__ __device__ __forceinline__ void tf_round(unsigned& x0, unsigned& x1, int r) {
  x0 += x1;
  x1 = (x1 << r) | (x1 >> (32 - r));
  x1 ^= x0;
}
__host__ __device__ __forceinline__ void tf2x32(unsigned k0, unsigned k1,
                                                unsigned& x0, unsigned& x1) {
  unsigned ks2 = k0 ^ k1 ^ 0x1BD11BDAu;
  x0 += k0; x1 += k1;
  tf_round(x0,x1,13); tf_round(x0,x1,15); tf_round(x0,x1,26); tf_round(x0,x1,6);
  x0 += k1; x1 += ks2 + 1u;
  tf_round(x0,x1,17); tf_round(x0,x1,29); tf_round(x0,x1,16); tf_round(x0,x1,24);
  x0 += ks2; x1 += k0 + 2u;
  tf_round(x0,x1,13); tf_round(x0,x1,15); tf_round(x0,x1,26); tf_round(x0,x1,6);
  x0 += k0; x1 += k1 + 3u;
  tf_round(x0,x1,17); tf_round(x0,x1,29); tf_round(x0,x1,16); tf_round(x0,x1,24);
  x0 += k1; x1 += ks2 + 4u;
  tf_round(x0,x1,13); tf_round(x0,x1,15); tf_round(x0,x1,26); tf_round(x0,x1,6);
  x0 += ks2; x1 += k0 + 5u;
}

// bits -> N(0,1), replicating jax.random.normal f32 path (partitionable threefry)
__device__ __forceinline__ float bits_to_normal(unsigned bits) {
  float f = __uint_as_float((bits >> 9) | 0x3f800000u) - 1.0f;  // [0,1)
  const float LO = -0.99999994f;
  float u = fmaf(f, 2.0f, LO);
  u = fmaxf(u, LO);
  float w = -log1pf(-u * u);
  float p;
  if (w < 5.0f) {
    w -= 2.5f;
    p = 2.81022636e-08f;
    p = fmaf(p, w, 3.43273939e-07f);
    p = fmaf(p, w, -3.5233877e-06f);
    p = fmaf(p, w, -4.39150654e-06f);
    p = fmaf(p, w, 0.00021858087f);
    p = fmaf(p, w, -0.00125372503f);
    p = fmaf(p, w, -0.00417768164f);
    p = fmaf(p, w, 0.246640727f);
    p = fmaf(p, w, 1.50140941f);
  } else {
    w = sqrtf(w) - 3.0f;
    p = -0.000200214257f;
    p = fmaf(p, w, 0.000100950558f);
    p = fmaf(p, w, 0.00134934322f);
    p = fmaf(p, w, -0.00367342844f);
    p = fmaf(p, w, 0.00573950773f);
    p = fmaf(p, w, -0.0076224613f);
    p = fmaf(p, w, 0.00943887047f);
    p = fmaf(p, w, 1.00167406f);
    p = fmaf(p, w, 2.83297682f);
  }
  return 1.41421356f * (p * u);
}

// ================= CSR build (once per launch; edge_index reused 4x) =================
__global__ __launch_bounds__(256) void hist_kern(const int* __restrict__ eiR,
                                                 const int* __restrict__ eiP,
                                                 int* __restrict__ cntR,
                                                 int* __restrict__ cntP) {
  int i = blockIdx.x * 256 + threadIdx.x;  // 0..131071
  const int* ei = (i < kE) ? eiR : eiP;
  int* cnt = (i < kE) ? cntR : cntP;
  int e = i & (kE - 1);
  atomicAdd(&cnt[ei[kE + e]], 1);
}

// 2 blocks (one per graph), 256 threads: 32 elems/thread + hierarchical block scan
__global__ __launch_bounds__(256) void scan_kern(const int* __restrict__ cntR,
                                                 int* __restrict__ rpR, int* __restrict__ offR,
                                                 const int* __restrict__ cntP,
                                                 int* __restrict__ rpP, int* __restrict__ offP) {
  const int* cnt = blockIdx.x ? cntP : cntR;
  int* rp = blockIdx.x ? rpP : rpR;
  int* off = blockIdx.x ? offP : offR;
  int t = threadIdx.x;
  int base = t * 32;
  int v[32];
#pragma unroll
  for (int i = 0; i < 32; ++i) v[i] = cnt[base + i];
  int sum = 0;
#pragma unroll
  for (int i = 0; i < 32; ++i) sum += v[i];
  int lane = t & 63, w = t >> 6;
  int incl = sum;
#pragma unroll
  for (int o = 1; o < 64; o <<= 1) {
    int y = __shfl_up(incl, o);
    if (lane >= o) incl += y;
  }
  __shared__ int wsum[4];
  if (lane == 63) wsum[w] = incl;
  __syncthreads();
  int woff = 0;
#pragma unroll
  for (int i = 0; i < 4; ++i) if (i < w) woff += wsum[i];
  int running = woff + incl - sum;
#pragma unroll
  for (int i = 0; i < 32; ++i) {
    rp[base + i] = running;
    off[base + i] = running;
    running += v[i];
  }
  if (t == 0) rp[kNTOT] = kE;
}

__global__ __launch_bounds__(256) void scatter_kern(
    const int* __restrict__ eiR, const int* __restrict__ eiP,
    int* __restrict__ offR, int* __restrict__ offP,
    int* __restrict__ permR, int* __restrict__ permP,
    int* __restrict__ srcsR, int* __restrict__ srcsP) {
  int i = blockIdx.x * 256 + threadIdx.x;
  const int* ei = (i < kE) ? eiR : eiP;
  int* off = (i < kE) ? offR : offP;
  int* perm = (i < kE) ? permR : permP;
  int* srcs = (i < kE) ? srcsR : srcsP;
  int e = i & (kE - 1);
  int dst = ei[kE + e];
  int pos = atomicAdd(&off[dst], 1);
  perm[pos] = e;
  srcs[pos] = ei[e];
}

// ================= msg GEMM (both graphs): msg[i] = relu(x[srcs[i]]@Wm + ef[perm[i]]@We)
template <int KX>
__global__ __launch_bounds__(256) void msg_gemm(
    const float* __restrict__ xR, const float* __restrict__ efR,
    const int* __restrict__ srcsR, const int* __restrict__ permR,
    float* __restrict__ msgR,
    const float* __restrict__ xP, const float* __restrict__ efP,
    const int* __restrict__ srcsP, const int* __restrict__ permP,
    float* __restrict__ msgP,
    const float* __restrict__ Wm, const float* __restrict__ We) {
  constexpr int KT = KX + 16;
  __shared__ float sA[KT][68];   // transposed A-tile: [k][edge]
  __shared__ float sW[KT][68];   // [k][j]
  bool isP = blockIdx.x >= 1024;
  const float* x = isP ? xP : xR;
  const float* ef = isP ? efP : efR;
  const int* srcs = isP ? srcsP : srcsR;
  const int* perm = isP ? permP : permR;
  float* msg = isP ? msgP : msgR;
  int i0 = (blockIdx.x & 1023) * 64;
  int t = threadIdx.x;
#pragma unroll
  for (int idx = 0; idx < KT * 64 / 1024; ++idx) {
    int q = t * 4 + idx * 1024;
    int k = q >> 6, j = q & 63;
    const float* sp = (k < KX) ? (Wm + k * 64 + j) : (We + (k - KX) * 64 + j);
    float4 v = *reinterpret_cast<const float4*>(sp);
    *reinterpret_cast<float4*>(&sW[k][j]) = v;
  }
#pragma unroll
  for (int idx = 0; idx < KT * 64 / 1024; ++idx) {
    int q = t * 4 + idx * 1024;
    int r = q / KT;
    int k = q % KT;   // 4-aligned
    const float* rptr = (k < KX) ? (x + (size_t)srcs[i0 + r] * KX + k)
                                 : (ef + (size_t)perm[i0 + r] * 16 + (k - KX));
    float4 v = *reinterpret_cast<const float4*>(rptr);
    sA[k + 0][r] = v.x; sA[k + 1][r] = v.y; sA[k + 2][r] = v.z; sA[k + 3][r] = v.w;
  }
  __syncthreads();
  int tn = (t & 15) * 4;
  int tj = (t >> 4) * 4;
  float acc[4][4] = {};
#pragma unroll 8
  for (int k = 0; k < KT; ++k) {
    float4 a = *reinterpret_cast<const float4*>(&sA[k][tn]);
    float4 b = *reinterpret_cast<const float4*>(&sW[k][tj]);
    acc[0][0] = fmaf(a.x, b.x, acc[0][0]); acc[0][1] = fmaf(a.x, b.y, acc[0][1]);
    acc[0][2] = fmaf(a.x, b.z, acc[0][2]); acc[0][3] = fmaf(a.x, b.w, acc[0][3]);
    acc[1][0] = fmaf(a.y, b.x, acc[1][0]); acc[1][1] = fmaf(a.y, b.y, acc[1][1]);
    acc[1][2] = fmaf(a.y, b.z, acc[1][2]); acc[1][3] = fmaf(a.y, b.w, acc[1][3]);
    acc[2][0] = fmaf(a.z, b.x, acc[2][0]); acc[2][1] = fmaf(a.z, b.y, acc[2][1]);
    acc[2][2] = fmaf(a.z, b.z, acc[2][2]); acc[2][3] = fmaf(a.z, b.w, acc[2][3]);
    acc[3][0] = fmaf(a.w, b.x, acc[3][0]); acc[3][1] = fmaf(a.w, b.y, acc[3][1]);
    acc[3][2] = fmaf(a.w, b.z, acc[3][2]); acc[3][3] = fmaf(a.w, b.w, acc[3][3]);
  }
#pragma unroll
  for (int i = 0; i < 4; ++i) {
    float4 o;
    o.x = fmaxf(acc[i][0], 0.f); o.y = fmaxf(acc[i][1], 0.f);
    o.z = fmaxf(acc[i][2], 0.f); o.w = fmaxf(acc[i][3], 0.f);
    *reinterpret_cast<float4*>(&msg[(size_t)(i0 + tn + i) * 64 + tj]) = o;
  }
}

// ====== agg (dual-graph, 4096 blocks = 16384 waves for latency hiding) ======
__global__ __launch_bounds__(256) void agg_kern(
    const float* __restrict__ msgR, const int* __restrict__ rpR, float* __restrict__ aggR,
    const float* __restrict__ msgP, const int* __restrict__ rpP, float* __restrict__ aggP) {
  int lane = threadIdx.x & 63;
  int idx = blockIdx.x * 4 + (threadIdx.x >> 6);  // 0..16383
  const float* msg; const int* rp; float* agg;
  if (idx < kNTOT) { msg = msgR; rp = rpR; agg = aggR; }
  else { msg = msgP; rp = rpP; agg = aggP; idx -= kNTOT; }
  int s = rp[idx], e = rp[idx + 1];
  float acc = 0.f;
  for (int i = s; i < e; ++i) acc += msg[(size_t)i * 64 + lane];
  agg[(size_t)idx * 64 + lane] = acc;
}

// ====== node1 as dense tiled GEMM: h = relu(X@Ws + agg + b), 64x64 tile/block ======
__global__ __launch_bounds__(256) void node1_gemm(
    const float* __restrict__ xR, const float* __restrict__ aggR, float* __restrict__ hR,
    const float* __restrict__ xP, const float* __restrict__ aggP, float* __restrict__ hP,
    const float* __restrict__ Ws, const float* __restrict__ bias) {
  __shared__ float sX[64][68];   // [k][row]
  __shared__ float sW[64][68];   // [k][col]
  bool isP = blockIdx.x >= 128;
  const float* x = isP ? xP : xR;
  const float* agg = isP ? aggP : aggR;
  float* h = isP ? hP : hR;
  int n0 = (blockIdx.x & 127) * 64;
  int t = threadIdx.x;
#pragma unroll
  for (int idx = 0; idx < 4; ++idx) {
    int q = t * 4 + idx * 1024;
    int k = q >> 6, j = q & 63;
    *reinterpret_cast<float4*>(&sW[k][j]) = *reinterpret_cast<const float4*>(Ws + q);
    float4 v = *reinterpret_cast<const float4*>(x + (size_t)n0 * 64 + q);  // row k, col j
    sX[j + 0][k] = v.x; sX[j + 1][k] = v.y; sX[j + 2][k] = v.z; sX[j + 3][k] = v.w;
  }
  __syncthreads();
  int tn = (t & 15) * 4, tj = (t >> 4) * 4;
  float acc[4][4] = {};
#pragma unroll 8
  for (int k = 0; k < 64; ++k) {
    float4 a = *reinterpret_cast<const float4*>(&sX[k][tn]);
    float4 b = *reinterpret_cast<const float4*>(&sW[k][tj]);
    acc[0][0] = fmaf(a.x, b.x, acc[0][0]); acc[0][1] = fmaf(a.x, b.y, acc[0][1]);
    acc[0][2] = fmaf(a.x, b.z, acc[0][2]); acc[0][3] = fmaf(a.x, b.w, acc[0][3]);
    acc[1][0] = fmaf(a.y, b.x, acc[1][0]); acc[1][1] = fmaf(a.y, b.y, acc[1][1]);
    acc[1][2] = fmaf(a.y, b.z, acc[1][2]); acc[1][3] = fmaf(a.y, b.w, acc[1][3]);
    acc[2][0] = fmaf(a.z, b.x, acc[2][0]); acc[2][1] = fmaf(a.z, b.y, acc[2][1]);
    acc[2][2] = fmaf(a.z, b.z, acc[2][2]); acc[2][3] = fmaf(a.z, b.w, acc[2][3]);
    acc[3][0] = fmaf(a.w, b.x, acc[3][0]); acc[3][1] = fmaf(a.w, b.y, acc[3][1]);
    acc[3][2] = fmaf(a.w, b.z, acc[3][2]); acc[3][3] = fmaf(a.w, b.w, acc[3][3]);
  }
  float4 bv = *reinterpret_cast<const float4*>(bias + tj);
#pragma unroll
  for (int i = 0; i < 4; ++i) {
    int n = n0 + tn + i;
    float4 g = *reinterpret_cast<const float4*>(agg + (size_t)n * 64 + tj);
    float4 o;
    o.x = fmaxf(acc[i][0] + g.x + bv.x, 0.f);
    o.y = fmaxf(acc[i][1] + g.y + bv.y, 0.f);
    o.z = fmaxf(acc[i][2] + g.z + bv.z, 0.f);
    o.w = fmaxf(acc[i][3] + g.w + bv.w, 0.f);
    *reinterpret_cast<float4*>(&h[(size_t)n * 64 + tj]) = o;
  }
}

// ====== node2u as two chained tiled GEMMs: o = relu(rf@Ws2 + agg + g2b); u = o@W1 (+b1) ==
__global__ __launch_bounds__(256) void node2u_gemm(
    const float* __restrict__ rfR, const float* __restrict__ aggR, float* __restrict__ uR,
    const float* __restrict__ rfP, const float* __restrict__ aggP, float* __restrict__ uP,
    const float* __restrict__ Ws2, const float* __restrict__ g2b,
    const float* __restrict__ W1, const float* __restrict__ b1) {
  __shared__ float sRF[32][68];  // [k][row]
  __shared__ float sW2[32][68];  // [k][col]
  __shared__ float sW1[64][68];  // [k][col]
  __shared__ float sO[64][68];   // [k][row]
  bool isP = blockIdx.x >= 128;
  const float* rf = isP ? rfP : rfR;
  const float* agg = isP ? aggP : aggR;
  float* u = isP ? uP : uR;
  int n0 = (blockIdx.x & 127) * 64;
  int t = threadIdx.x;
#pragma unroll
  for (int idx = 0; idx < 4; ++idx) {
    int q = t * 4 + idx * 1024;
    *reinterpret_cast<float4*>(&sW1[q >> 6][q & 63]) = *reinterpret_cast<const float4*>(W1 + q);
  }
#pragma unroll
  for (int idx = 0; idx < 2; ++idx) {
    int q = t * 4 + idx * 1024;
    *reinterpret_cast<float4*>(&sW2[q >> 6][q & 63]) = *reinterpret_cast<const float4*>(Ws2 + q);
    int r = q >> 5, kk = q & 31;
    float4 v = *reinterpret_cast<const float4*>(rf + (size_t)(n0 + r) * 32 + kk);
    sRF[kk + 0][r] = v.x; sRF[kk + 1][r] = v.y; sRF[kk + 2][r] = v.z; sRF[kk + 3][r] = v.w;
  }
  __syncthreads();
  int tn = (t & 15) * 4, tj = (t >> 4) * 4;
  float acc[4][4] = {};
#pragma unroll 8
  for (int k = 0; k < 32; ++k) {
    float4 a = *reinterpret_cast<const float4*>(&sRF[k][tn]);
    float4 b = *reinterpret_cast<const float4*>(&sW2[k][tj]);
    acc[0][0] = fmaf(a.x, b.x, acc[0][0]); acc[0][1] = fmaf(a.x, b.y, acc[0][1]);
    acc[0][2] = fmaf(a.x, b.z, acc[0][2]); acc[0][3] = fmaf(a.x, b.w, acc[0][3]);
    acc[1][0] = fmaf(a.y, b.x, acc[1][0]); acc[1][1] = fmaf(a.y, b.y, acc[1][1]);
    acc[1][2] = fmaf(a.y, b.z, acc[1][2]); acc[1][3] = fmaf(a.y, b.w, acc[1][3]);
    acc[2][0] = fmaf(a.z, b.x, acc[2][0]); acc[2][1] = fmaf(a.z, b.y, acc[2][1]);
    acc[2][2] = fmaf(a.z, b.z, acc[2][2]); acc[2][3] = fmaf(a.z, b.w, acc[2][3]);
    acc[3][0] = fmaf(a.w, b.x, acc[3][0]); acc[3][1] = fmaf(a.w, b.y, acc[3][1]);
    acc[3][2] = fmaf(a.w, b.z, acc[3][2]); acc[3][3] = fmaf(a.w, b.w, acc[3][3]);
  }
  float4 bg = *reinterpret_cast<const float4*>(g2b + tj);
#pragma unroll
  for (int i = 0; i < 4; ++i) {
    int n = n0 + tn + i;
    float4 g = *reinterpret_cast<const float4*>(agg + (size_t)n * 64 + tj);
    sO[tj + 0][tn + i] = fmaxf(acc[i][0] + g.x + bg.x, 0.f);
    sO[tj + 1][tn + i] = fmaxf(acc[i][1] + g.y + bg.y, 0.f);
    sO[tj + 2][tn + i] = fmaxf(acc[i][2] + g.z + bg.z, 0.f);
    sO[tj + 3][tn + i] = fmaxf(acc[i][3] + g.w + bg.w, 0.f);
  }
  __syncthreads();
  float acc2[4][4] = {};
#pragma unroll 8
  for (int k = 0; k < 64; ++k) {
    float4 a = *reinterpret_cast<const float4*>(&sO[k][tn]);
    float4 b = *reinterpret_cast<const float4*>(&sW1[k][tj]);
    acc2[0][0] = fmaf(a.x, b.x, acc2[0][0]); acc2[0][1] = fmaf(a.x, b.y, acc2[0][1]);
    acc2[0][2] = fmaf(a.x, b.z, acc2[0][2]); acc2[0][3] = fmaf(a.x, b.w, acc2[0][3]);
    acc2[1][0] = fmaf(a.y, b.x, acc2[1][0]); acc2[1][1] = fmaf(a.y, b.y, acc2[1][1]);
    acc2[1][2] = fmaf(a.y, b.z, acc2[1][2]); acc2[1][3] = fmaf(a.y, b.w, acc2[1][3]);
    acc2[2][0] = fmaf(a.z, b.x, acc2[2][0]); acc2[2][1] = fmaf(a.z, b.y, acc2[2][1]);
    acc2[2][2] = fmaf(a.z, b.z, acc2[2][2]); acc2[2][3] = fmaf(a.z, b.w, acc2[2][3]);
    acc2[3][0] = fmaf(a.w, b.x, acc2[3][0]); acc2[3][1] = fmaf(a.w, b.y, acc2[3][1]);
    acc2[3][2] = fmaf(a.w, b.z, acc2[3][2]); acc2[3][3] = fmaf(a.w, b.w, acc2[3][3]);
  }
  float4 b1v = make_float4(0.f, 0.f, 0.f, 0.f);
  if (!isP) b1v = *reinterpret_cast<const float4*>(b1 + tj);
#pragma unroll
  for (int i = 0; i < 4; ++i) {
    int n = n0 + tn + i;
    float4 o;
    o.x = acc2[i][0] + b1v.x; o.y = acc2[i][1] + b1v.y;
    o.z = acc2[i][2] + b1v.z; o.w = acc2[i][3] + b1v.w;
    *reinterpret_cast<float4*>(&u[(size_t)n * 64 + tj]) = o;
  }
}

// ---------------- M_hat[b,r,p] = sum_d h_r[b,r,d]*h_p[b,p,d] ----------------
__global__ __launch_bounds__(64) void mhat_kern(const float* __restrict__ hR,
                                                const float* __restrict__ hP,
                                                float* __restrict__ Mhat) {
  __shared__ float hr[16][66];
  __shared__ float hp[128][66];
  int b = blockIdx.x >> 3;
  int r0 = (blockIdx.x & 7) * 16;
  int t = threadIdx.x;
  const float* hrG = hR + ((size_t)b * 128 + r0) * 64;
#pragma unroll
  for (int s = 0; s < 16; ++s) { int i = t + 64 * s; hr[i >> 6][i & 63] = hrG[i]; }
  const float* hpG = hP + (size_t)b * 128 * 64;
#pragma unroll 8
  for (int s = 0; s < 128; ++s) { int i = t + 64 * s; hp[i >> 6][i & 63] = hpG[i]; }
  __syncthreads();
  int tx = t & 31;
  int ty = t >> 5;
  float acc[8][4] = {};
  for (int d = 0; d < 64; ++d) {
    float a[8], bb[4];
#pragma unroll
    for (int ii = 0; ii < 8; ++ii) a[ii] = hr[ty + 2 * ii][d];
#pragma unroll
    for (int i = 0; i < 4; ++i) bb[i] = hp[tx + 32 * i][d];
#pragma unroll
    for (int ii = 0; ii < 8; ++ii)
#pragma unroll
      for (int i = 0; i < 4; ++i) acc[ii][i] = fmaf(a[ii], bb[i], acc[ii][i]);
  }
  float* outp = Mhat + ((size_t)b * 128 + r0) * 128;
#pragma unroll
  for (int ii = 0; ii < 8; ++ii)
#pragma unroll
    for (int i = 0; i < 4; ++i)
      outp[(size_t)(ty + 2 * ii) * 128 + tx + 32 * i] = acc[ii][i];
}

// ======== fused per-batch: RNG (threefry) + softmax(Mhat[b]) + rf_p = M^T @ rf_r ========
__global__ __launch_bounds__(256) void softrfp_kern(
    const float* __restrict__ Mhat, float* __restrict__ M0out,
    float* __restrict__ rfr, float* __restrict__ rfp,
    unsigned fk0, unsigned fk1) {
  __shared__ __align__(16) float sM[128][132];
  __shared__ __align__(16) float rr[128][32];
  int b = blockIdx.x;
  int t = threadIdx.x;
  unsigned gbase = (unsigned)b * 4096u;
#pragma unroll
  for (int q = 0; q < 16; ++q) {
    int il = q * 256 + t;
    unsigned x0 = 0u, x1 = gbase + (unsigned)il;   // counter (hi,lo) = (0, i)
    tf2x32(fk0, fk1, x0, x1);
    float nv = bits_to_normal(x0 ^ x1);
    rr[il >> 5][il & 31] = nv;
    rfr[gbase + il] = nv;
  }
  const float4* src = reinterpret_cast<const float4*>(Mhat + (size_t)b * 16384);
#pragma unroll
  for (int q = 0; q < 16; ++q) {
    int idx = q * 256 + t;
    float4 v = src[idx];
    *reinterpret_cast<float4*>(&sM[idx >> 5][(idx & 31) * 4]) = v;
  }
  __syncthreads();
  int lane = t & 63, w = t >> 6;
  for (int row = w; row < 128; row += 4) {
    float v0 = sM[row][2 * lane], v1 = sM[row][2 * lane + 1];
    float mx = fmaxf(v0, v1);
#pragma unroll
    for (int o = 32; o > 0; o >>= 1) mx = fmaxf(mx, __shfl_xor(mx, o));
    float e0 = __expf(v0 - mx), e1 = __expf(v1 - mx);
    float s = e0 + e1;
#pragma unroll
    for (int o = 32; o > 0; o >>= 1) s += __shfl_xor(s, o);
    float inv = 1.0f / s;
    sM[row][2 * lane] = e0 * inv;
    sM[row][2 * lane + 1] = e1 * inv;
  }
  __syncthreads();
  if (M0out) {
    float4* dst = reinterpret_cast<float4*>(M0out + (size_t)b * 16384);
#pragma unroll
    for (int q = 0; q < 16; ++q) {
      int idx = q * 256 + t;
      dst[idx] = *reinterpret_cast<const float4*>(&sM[idx >> 5][(idx & 31) * 4]);
    }
  }
  int p = t >> 1, hf = t & 1;
  float acc[16] = {};
  for (int r = 0; r < 128; ++r) {
    float m = sM[r][p];
#pragma unroll
    for (int i = 0; i < 16; ++i) acc[i] = fmaf(m, rr[r][hf * 16 + i], acc[i]);
  }
  float4* dst = reinterpret_cast<float4*>(rfp + ((size_t)b * 128 + p) * 32 + hf * 16);
  dst[0] = make_float4(acc[0], acc[1], acc[2], acc[3]);
  dst[1] = make_float4(acc[4], acc[5], acc[6], acc[7]);
  dst[2] = make_float4(acc[8], acc[9], acc[10], acc[11]);
  dst[3] = make_float4(acc[12], acc[13], acc[14], acc[15]);
}

// ---------------- final softmax (rows of 128) -> out ----------------
__global__ __launch_bounds__(256) void softmax_out_kern(
    const float* __restrict__ Mhat, float* __restrict__ outDst) {
  int lane = threadIdx.x & 63;
  int row = blockIdx.x * 4 + (threadIdx.x >> 6);
  const float2* src = reinterpret_cast<const float2*>(Mhat + (size_t)row * 128);
  float2 v = src[lane];
  float mx = fmaxf(v.x, v.y);
#pragma unroll
  for (int o = 32; o > 0; o >>= 1) mx = fmaxf(mx, __shfl_xor(mx, o));
  float e0 = __expf(v.x - mx), e1 = __expf(v.y - mx);
  float s = e0 + e1;
#pragma unroll
  for (int o = 32; o > 0; o >>= 1) s += __shfl_xor(s, o);
  float inv = 1.0f / s;
  float2 r2; r2.x = e0 * inv; r2.y = e1 * inv;
  reinterpret_cast<float2*>(outDst + (size_t)row * 128)[lane] = r2;
}

// ---------------- upd: M_hat[b,r,p] += sum_j relu(u_r[r,j]-u_p[p,j])*W2[j] + b2 ------
__global__ __launch_bounds__(128) void upd_kern(
    const float* __restrict__ uR, const float* __restrict__ uP,
    const float* __restrict__ W2, const float* __restrict__ b2p,
    float* __restrict__ Mhat) {
  __shared__ float sur[16][66];
  __shared__ float sup[128][66];
  __shared__ float sw2[64];
  int b = blockIdx.x >> 3;
  int r0 = (blockIdx.x & 7) * 16;
  int t = threadIdx.x;
  const float* urG = uR + ((size_t)b * 128 + r0) * 64;
#pragma unroll
  for (int s = 0; s < 8; ++s) { int i = t + 128 * s; sur[i >> 6][i & 63] = urG[i]; }
  const float* upG = uP + (size_t)b * 128 * 64;
#pragma unroll 8
  for (int s = 0; s < 64; ++s) { int i = t + 128 * s; sup[i >> 6][i & 63] = upG[i]; }
  if (t < 64) sw2[t] = W2[t];
  __syncthreads();
  int tx = t & 31, ty = t >> 5;
  float acc[4][4] = {};
  for (int j = 0; j < 64; ++j) {
    float w2v = sw2[j];
    float a[4], bb[4];
#pragma unroll
    for (int ii = 0; ii < 4; ++ii) a[ii] = sur[ty + 4 * ii][j];
#pragma unroll
    for (int i = 0; i < 4; ++i) bb[i] = sup[tx + 32 * i][j];
#pragma unroll
    for (int ii = 0; ii < 4; ++ii)
#pragma unroll
      for (int i = 0; i < 4; ++i)
        acc[ii][i] = fmaf(fmaxf(a[ii] - bb[i], 0.f), w2v, acc[ii][i]);
  }
  float b2v = b2p[0];
  float* mrow = Mhat + ((size_t)b * 128 + r0) * 128;
#pragma unroll
  for (int ii = 0; ii < 4; ++ii) {
    int r = ty + 4 * ii;
#pragma unroll
    for (int i = 0; i < 4; ++i) {
      int p = tx + 32 * i;
      mrow[(size_t)r * 128 + p] += acc[ii][i] + b2v;
    }
  }
}

extern "C" void kernel_launch(void* const* d_in, const int* in_sizes, int n_in,
                              void* d_out, int out_size, void* d_ws, size_t ws_size,
                              hipStream_t stream) {
  (void)in_sizes; (void)n_in; (void)out_size; (void)ws_size;
  const float* x_r  = (const float*)d_in[0];
  const int*   ei_r = (const int*)d_in[1];
  const float* ef_r = (const float*)d_in[2];
  const float* x_p  = (const float*)d_in[3];
  const int*   ei_p = (const int*)d_in[4];
  const float* ef_p = (const float*)d_in[5];
  const float* g1_Ws = (const float*)d_in[8];
  const float* g1_Wm = (const float*)d_in[9];
  const float* g1_We = (const float*)d_in[10];
  const float* g1_b  = (const float*)d_in[11];
  const float* g2_Ws = (const float*)d_in[12];
  const float* g2_Wm = (const float*)d_in[13];
  const float* g2_We = (const float*)d_in[14];
  const float* g2_b  = (const float*)d_in[15];
  const float* W1 = (const float*)d_in[16];
  const float* b1 = (const float*)d_in[17];
  const float* W2 = (const float*)d_in[18];
  const float* b2 = (const float*)d_in[19];
  float* out = (float*)d_out;

  float* ws = (float*)d_ws;
  float* h_r   = ws;                 // 524288
  float* h_p   = h_r + 524288;       // 524288
  float* Mhat  = h_p + 524288;       // 1048576
  float* rfr   = Mhat + 1048576;     // 262144
  float* rfp   = rfr + 262144;       // 262144
  float* u_r   = rfp + 262144;       // 524288
  float* u_p   = u_r + 524288;       // 524288
  float* agg_r = u_p + 524288;       // 524288
  float* agg_p = agg_r + 524288;     // 524288
  float* msg_r = agg_p + 524288;     // 4194304
  float* msg_p = msg_r + 4194304;    // 4194304
  int* ib      = (int*)(msg_p + 4194304);
  int* cnt_r  = ib;                  // 8192
  int* cnt_p  = cnt_r + 8192;        // 8192
  int* off_r  = cnt_p + 8192;        // 8192
  int* off_p  = off_r + 8192;        // 8192
  int* rp_r   = off_p + 8192;        // 8193
  int* rp_p   = rp_r + 8193;         // 8193
  int* perm_r = rp_p + 8193;         // 65536
  int* perm_p = perm_r + 65536;      // 65536
  int* srcs_r = perm_p + 65536;      // 65536
  int* srcs_p = srcs_r + 65536;      // 65536

  // ---- CSR build (once; reused by all 4 message passes) ----
  hipMemsetAsync(cnt_r, 0, 2 * 8192 * sizeof(int), stream);
  hist_kern<<<512, 256, 0, stream>>>(ei_r, ei_p, cnt_r, cnt_p);
  scan_kern<<<2, 256, 0, stream>>>(cnt_r, rp_r, off_r, cnt_p, rp_p, off_p);
  scatter_kern<<<512, 256, 0, stream>>>(ei_r, ei_p, off_r, off_p,
                                        perm_r, perm_p, srcs_r, srcs_p);

  // ---- gnn1 ----
  msg_gemm<64><<<2048, 256, 0, stream>>>(x_r, ef_r, srcs_r, perm_r, msg_r,
                                         x_p, ef_p, srcs_p, perm_p, msg_p,
                                         g1_Wm, g1_We);
  agg_kern<<<4096, 256, 0, stream>>>(msg_r, rp_r, agg_r, msg_p, rp_p, agg_p);
  node1_gemm<<<256, 256, 0, stream>>>(x_r, agg_r, h_r, x_p, agg_p, h_p, g1_Ws, g1_b);
  mhat_kern<<<512, 64, 0, stream>>>(h_r, h_p, Mhat);

  for (int it = 0; it < 3; ++it) {
    unsigned fk0 = 0u, fk1 = (unsigned)it;
    tf2x32(0u, 42u, fk0, fk1);   // folded key, host-side
    softrfp_kern<<<64, 256, 0, stream>>>(Mhat, it == 0 ? out : nullptr,
                                         rfr, rfp, fk0, fk1);
    msg_gemm<32><<<2048, 256, 0, stream>>>(rfr, ef_r, srcs_r, perm_r, msg_r,
                                           rfp, ef_p, srcs_p, perm_p, msg_p,
                                           g2_Wm, g2_We);
    agg_kern<<<4096, 256, 0, stream>>>(msg_r, rp_r, agg_r, msg_p, rp_p, agg_p);
    node2u_gemm<<<256, 256, 0, stream>>>(rfr, agg_r, u_r, rfp, agg_p, u_p,
                                         g2_Ws, g2_b, W1, b1);
    upd_kern<<<512, 128, 0, stream>>>(u_r, u_p, W2, b2, Mhat);
  }
  softmax_out_kern<<<2048, 256, 0, stream>>>(Mhat, out + 1048576);
}